// Round 3
// baseline (155.293 us; speedup 1.0000x reference)
//
#include <hip/hip_runtime.h>

// GaussianSplatter: out[(bl,c),(y,x)] = clip( sum_p A[(bl,c),p] * KY[p,y]*KX[p,x] )
// M=4096 (=64 patches * 64 ch), N=2304 (=48*48 pixels), K=2304 (=48*48 points)
// K-band: KY[p,y]!=0  <=>  y-10.5 < (47/48)*i < y+11.5  (i = p/48)
// GEMM: 128x64 tiles, 4 waves, double-buffered LDS, 2-phase prefetch,
//       XOR-swizzled LDS via pre-swizzled global_load_lds sources (rule 21 / m173).

#define NPTS 2304
#define KD   2304
#define HH   192

typedef _Float16 f16;
typedef _Float16 f16x8 __attribute__((ext_vector_type(8)));
typedef float f32x4 __attribute__((ext_vector_type(4)));

__device__ __forceinline__ void gload16(const f16* g, f16* l) {
    __builtin_amdgcn_global_load_lds((const __attribute__((address_space(1))) void*)g,
                                     (__attribute__((address_space(3))) void*)l,
                                     16, 0, 0);
}

// one bilinear tap of the padded 1-D gaussian: taps t in [13,33] hold exp(-(0.5t-11.5)^2 * inv2s)
__device__ __forceinline__ float gtap(float t, float inv2s) {
    float ax = 0.5f * t - 11.5f;
    float g = expf(-ax * ax * inv2s);
    return (t >= 12.5f && t <= 33.5f) ? g : 0.0f;
}

// KY_T[y][p] (opacity folded), KX_T[x][p]
__global__ void build_kykx(const float* __restrict__ sx, const float* __restrict__ sy,
                           const float* __restrict__ op,
                           float* __restrict__ KY_T, float* __restrict__ KX_T) {
    int flat = blockIdx.x * 256 + threadIdx.x;      // 48*2304 = 110592
    if (flat >= 48 * NPTS) return;
    int pos = flat / NPTS;
    int p   = flat - pos * NPTS;
    int i = p / 48;
    int j = p - i * 48;
    float sxv = sx[p], syv = sy[p], opv = op[p];
    float invx = 0.5f / (sxv * sxv);  // h-axis uses sigma_x (reference: xx2/sx2 on axis 1)
    float invy = 0.5f / (syv * syv);

    float py = (float)pos + 23.5f - (47.0f / 48.0f) * (float)i;
    float y0 = floorf(py), fy = py - y0;
    KY_T[flat] = opv * (gtap(y0, invx) * (1.0f - fy) + gtap(y0 + 1.0f, invx) * fy);

    float px = (float)pos + 23.5f - (47.0f / 48.0f) * (float)j;
    float x0 = floorf(px), fx = px - x0;
    KX_T[flat] = gtap(x0, invy) * (1.0f - fx) + gtap(x0 + 1.0f, invy) * fx;
}

// Kt[hw][p] = (f16)(KY_T[y][p]*KX_T[x][p]) ; 8 points/thread, vectorized
__global__ void build_kt(const float* __restrict__ KY_T, const float* __restrict__ KX_T,
                         f16* __restrict__ Kt) {
    int idx = blockIdx.x * 256 + threadIdx.x;       // 2304*288 = 663552 chunks
    int hw = idx / 288;
    int p0 = (idx - hw * 288) * 8;
    int y = hw / 48, x = hw - y * 48;
    const float4* ky = (const float4*)(KY_T + (size_t)y * NPTS + p0);
    const float4* kx = (const float4*)(KX_T + (size_t)x * NPTS + p0);
    float4 a0 = ky[0], a1 = ky[1];
    float4 b0 = kx[0], b1 = kx[1];
    f16x8 r;
    r[0] = (f16)(a0.x * b0.x); r[1] = (f16)(a0.y * b0.y);
    r[2] = (f16)(a0.z * b0.z); r[3] = (f16)(a0.w * b0.w);
    r[4] = (f16)(a1.x * b1.x); r[5] = (f16)(a1.y * b1.y);
    r[6] = (f16)(a1.z * b1.z); r[7] = (f16)(a1.w * b1.w);
    *(f16x8*)(Kt + (size_t)hw * NPTS + p0) = r;
}

// A[m][p] fp16, m = bl*64 + c, p = i*48 + j ; 8 points/thread (never crosses a patch row)
__global__ void pack_A(const float* __restrict__ inp, f16* __restrict__ A) {
    int idx = blockIdx.x * 256 + threadIdx.x;       // 4096*288 = 1179648 chunks
    int m = idx / 288;
    int p0 = (idx - m * 288) * 8;
    int i = p0 / 48, j = p0 - i * 48;               // j in {0,8,...,40}, j+7 <= 47
    int bl = m >> 6, c = m & 63;
    int b = bl >> 4, pr = (bl >> 2) & 3, pc = bl & 3;
    const float* src = inp + ((size_t)(b * 64 + c) * HH + pr * 48 + i) * HH + pc * 48 + j;
    float4 a0 = *(const float4*)src;
    float4 a1 = *(const float4*)(src + 4);
    f16x8 r;
    r[0] = (f16)a0.x; r[1] = (f16)a0.y; r[2] = (f16)a0.z; r[3] = (f16)a0.w;
    r[4] = (f16)a1.x; r[5] = (f16)a1.y; r[6] = (f16)a1.z; r[7] = (f16)a1.w;
    *(f16x8*)(A + (size_t)m * KD + p0) = r;
}

// C[m][n] = sum_k A[m][k] * Bt[n][k], k restricted to the i-band of this n-tile.
// LDS swizzle: slot (row, chunk cs) holds global k-chunk cs ^ ((row>>1)&3); the
// inverse permutation is baked into each lane's gload_lds global source offset.
__global__ __launch_bounds__(256) void gemm_splat(const f16* __restrict__ A,
                                                  const f16* __restrict__ Bt,
                                                  float* __restrict__ out) {
    __shared__ __attribute__((aligned(16))) f16 As[2 * 4096];   // [2][128][32]
    __shared__ __attribute__((aligned(16))) f16 Bs[2 * 2048];   // [2][64][32]

    int tid  = threadIdx.x;
    int lane = tid & 63;
    int w    = tid >> 6;
    int wr   = w >> 1, wc = w & 1;       // wave -> (64-row, 32-col) quadrant
    int bx   = blockIdx.x;
    int m0   = (bx / 36) * 128;          // 36 n-tiles of 64
    int n0   = (bx % 36) * 64;

    // i-band for this n-tile (margin +-1 i; extra i's are exact zeros in Kt)
    int y_min = n0 / 48;
    int y_max = (n0 + 63) / 48;
    int i_lo = max(0,  (int)floorf((y_min - 10.5f) * (48.0f / 47.0f)));
    int i_hi = min(47, (int)ceilf ((y_max + 11.5f) * (48.0f / 47.0f)));
    int k_lo = (i_lo * 48) & ~31;
    int k_hi = min(KD, ((i_hi + 1) * 48 + 31) & ~31);
    int nt   = (k_hi - k_lo) >> 5;

    // staging: lane l -> row base+ (l>>2), chunk l&3; source k-chunk pre-swizzled
    int srow = lane >> 2;
    int sk   = (((lane & 3) ^ ((lane >> 3) & 3)) << 3);
    const f16* Abase = A  + (size_t)(m0 + w * 32 + srow) * KD + sk;   // rows w*32 .. +31 (2 insts)
    const f16* Bbase = Bt + (size_t)(n0 + w * 16 + srow) * KD + sk;   // rows w*16 .. +15

    // fragment reads: row = <mult of 16> + lrow; swizzled chunk = (lane>>4) ^ ((lrow>>1)&3)
    int lrow = lane & 15;
    int koe  = (((lane >> 4) ^ ((lane >> 1) & 3)) << 3);

    f32x4 acc[4][2] = {};

    #define STAGE(buf, k0)                                                      \
        do {                                                                    \
            gload16(Abase + (k0),           &As[(buf) * 4096 + (w * 2 + 0) * 512]); \
            gload16(Abase + 16 * KD + (k0), &As[(buf) * 4096 + (w * 2 + 1) * 512]); \
            gload16(Bbase + (k0),           &Bs[(buf) * 2048 + w * 512]);           \
        } while (0)

    STAGE(0, k_lo);
    __syncthreads();

    for (int t = 0; t < nt; ++t) {
        int cur = t & 1;
        if (t + 1 < nt) STAGE(cur ^ 1, k_lo + ((t + 1) << 5));

        f16x8 af[4], bf[2];
        #pragma unroll
        for (int mi = 0; mi < 4; ++mi)
            af[mi] = *(const f16x8*)&As[cur * 4096 + (wr * 64 + mi * 16 + lrow) * 32 + koe];
        #pragma unroll
        for (int ni = 0; ni < 2; ++ni)
            bf[ni] = *(const f16x8*)&Bs[cur * 2048 + (wc * 32 + ni * 16 + lrow) * 32 + koe];

        #pragma unroll
        for (int mi = 0; mi < 4; ++mi)
            #pragma unroll
            for (int ni = 0; ni < 2; ++ni)
                acc[mi][ni] = __builtin_amdgcn_mfma_f32_16x16x32_f16(af[mi], bf[ni], acc[mi][ni], 0, 0, 0);

        __syncthreads();
    }
    #undef STAGE

    // epilogue: D row = (lane>>4)*4 + r, col = lane&15 (m89-verified C/D layout); clip + fold
    #pragma unroll
    for (int mi = 0; mi < 4; ++mi) {
        #pragma unroll
        for (int r = 0; r < 4; ++r) {
            int m  = m0 + wr * 64 + mi * 16 + (lane >> 4) * 4 + r;
            int bl = m >> 6, c = m & 63;
            int b  = bl >> 4, pr = (bl >> 2) & 3, pc = bl & 3;
            float* orow = out + ((size_t)(b * 64 + c) * HH + pr * 48) * HH + pc * 48;
            #pragma unroll
            for (int ni = 0; ni < 2; ++ni) {
                int n = n0 + wc * 32 + ni * 16 + (lane & 15);
                int y = n / 48, x = n - y * 48;
                float v = acc[mi][ni][r];
                v = fminf(fmaxf(v, 0.0f), 1.0f);
                orow[y * HH + x] = v;
            }
        }
    }
}

extern "C" void kernel_launch(void* const* d_in, const int* in_sizes, int n_in,
                              void* d_out, int out_size, void* d_ws, size_t ws_size,
                              hipStream_t stream) {
    const float* inp = (const float*)d_in[0];
    const float* sx  = (const float*)d_in[1];
    const float* sy  = (const float*)d_in[2];
    const float* op  = (const float*)d_in[3];
    float* out = (float*)d_out;

    char* ws = (char*)d_ws;
    float* KY_T = (float*)ws;                               //   442368 B
    float* KX_T = (float*)(ws + 442368);                    //   442368 B
    f16*   Kt   = (f16*)(ws + 884736);                      // 10616832 B  [2304][2304]
    f16*   Ap   = (f16*)(ws + 884736 + 10616832);           // 18874368 B  [4096][2304]

    build_kykx<<<dim3(432),  dim3(256), 0, stream>>>(sx, sy, op, KY_T, KX_T);
    build_kt  <<<dim3(2592), dim3(256), 0, stream>>>(KY_T, KX_T, Kt);
    pack_A    <<<dim3(4608), dim3(256), 0, stream>>>(inp, Ap);
    gemm_splat<<<dim3(1152), dim3(256), 0, stream>>>(Ap, Kt, out);
}

// Round 4
// 138.389 us; speedup vs baseline: 1.1221x; 1.1221x over previous
//
#include <hip/hip_runtime.h>

// GaussianSplatter: out[(bl,c),(y,x)] = clip( sum_p A[(bl,c),p] * KY[p,y]*KX[p,x] )
// M=4096 (=64 patches * 64 ch), N=2304 (=48*48 pixels), K=2304 (=48*48 points)
// K-band: KY[p,y]!=0  <=>  y-10.5 < (47/48)*i < y+11.5  (i = p/48)
// GEMM: 128x128 tiles (R2 reuse) + dbuf/2-phase prefetch + XOR-swizzled LDS (R3, 0 conflicts)
//       + XCD-chunked block swizzle (T1, bijective 576=8*72: 4 m-panels per XCD).

#define NPTS 2304
#define KD   2304
#define HH   192

typedef _Float16 f16;
typedef _Float16 f16x8 __attribute__((ext_vector_type(8)));
typedef float f32x4 __attribute__((ext_vector_type(4)));

__device__ __forceinline__ void gload16(const f16* g, f16* l) {
    __builtin_amdgcn_global_load_lds((const __attribute__((address_space(1))) void*)g,
                                     (__attribute__((address_space(3))) void*)l,
                                     16, 0, 0);
}

// one bilinear tap of the padded 1-D gaussian: taps t in [13,33] hold exp(-(0.5t-11.5)^2 * inv2s)
__device__ __forceinline__ float gtap(float t, float inv2s) {
    float ax = 0.5f * t - 11.5f;
    float g = expf(-ax * ax * inv2s);
    return (t >= 12.5f && t <= 33.5f) ? g : 0.0f;
}

// Kt[hw][p] = (f16)(opacity[p] * KY(i(p),y) * KX(j(p),x)), gaussians computed inline.
// 8 points/thread; p0 8-aligned => all 8 points share i, j = j0..j0+7.
__global__ void build_kt(const float* __restrict__ sx, const float* __restrict__ sy,
                         const float* __restrict__ op, f16* __restrict__ Kt) {
    int idx = blockIdx.x * 256 + threadIdx.x;       // 2304*288 = 663552 chunks
    int hw = idx / 288;
    int p0 = (idx - hw * 288) * 8;
    int y = hw / 48, x = hw - y * 48;
    int i = p0 / 48, j0 = p0 - i * 48;

    // KY lerp coords (shared by all 8 points)
    float py = (float)y + 23.5f - (47.0f / 48.0f) * (float)i;
    float y0 = floorf(py), fy = py - y0;

    f16x8 r;
    #pragma unroll
    for (int u = 0; u < 8; ++u) {
        int p = p0 + u;
        float sxv = sx[p], syv = sy[p], opv = op[p];
        float invx = 0.5f / (sxv * sxv);  // h-axis uses sigma_x (ref: xx2/sx2 on axis 1)
        float invy = 0.5f / (syv * syv);
        float ky = opv * (gtap(y0, invx) * (1.0f - fy) + gtap(y0 + 1.0f, invx) * fy);
        float px = (float)x + 23.5f - (47.0f / 48.0f) * (float)(j0 + u);
        float x0 = floorf(px), fx = px - x0;
        float kx = gtap(x0, invy) * (1.0f - fx) + gtap(x0 + 1.0f, invy) * fx;
        r[u] = (f16)(ky * kx);
    }
    *(f16x8*)(Kt + (size_t)hw * NPTS + p0) = r;
}

// A[m][p] fp16, m = bl*64 + c, p = i*48 + j ; 8 points/thread (never crosses a patch row)
__global__ void pack_A(const float* __restrict__ inp, f16* __restrict__ A) {
    int idx = blockIdx.x * 256 + threadIdx.x;       // 4096*288 = 1179648 chunks
    int m = idx / 288;
    int p0 = (idx - m * 288) * 8;
    int i = p0 / 48, j = p0 - i * 48;               // j in {0,8,...,40}, j+7 <= 47
    int bl = m >> 6, c = m & 63;
    int b = bl >> 4, pr = (bl >> 2) & 3, pc = bl & 3;
    const float* src = inp + ((size_t)(b * 64 + c) * HH + pr * 48 + i) * HH + pc * 48 + j;
    float4 a0 = *(const float4*)src;
    float4 a1 = *(const float4*)(src + 4);
    f16x8 r;
    r[0] = (f16)a0.x; r[1] = (f16)a0.y; r[2] = (f16)a0.z; r[3] = (f16)a0.w;
    r[4] = (f16)a1.x; r[5] = (f16)a1.y; r[6] = (f16)a1.z; r[7] = (f16)a1.w;
    *(f16x8*)(A + (size_t)m * KD + p0) = r;
}

// C[m][n] = sum_k A[m][k] * Bt[n][k], k restricted to the i-band of this n-tile.
// LDS swizzle: slot (row, chunk cs) holds global k-chunk cs ^ ((row>>1)&3); the inverse
// permutation is baked into each lane's gload_lds global source offset (rule 21 / m173).
__global__ __launch_bounds__(256) void gemm_splat(const f16* __restrict__ A,
                                                  const f16* __restrict__ Bt,
                                                  float* __restrict__ out) {
    __shared__ __attribute__((aligned(16))) f16 As[2 * 4096];   // [2][128][32]
    __shared__ __attribute__((aligned(16))) f16 Bs[2 * 4096];   // [2][128][32]

    int tid  = threadIdx.x;
    int lane = tid & 63;
    int w    = tid >> 6;
    int wr   = w >> 1, wc = w & 1;       // wave -> (64,64) output quadrant
    // XCD-chunked bijective swizzle: 576 blocks = 8 XCDs x 72 (= 4 m-panels x 18 n-tiles)
    int bx   = blockIdx.x;
    int wg   = (bx & 7) * 72 + (bx >> 3);
    int m0   = (wg / 18) * 128;
    int n0   = (wg % 18) * 128;

    // i-band for this n-tile (margin +-1 i; extra i's are exact zeros in Kt)
    int y_min = n0 / 48;
    int y_max = (n0 + 127) / 48;
    int i_lo = max(0,  (int)floorf((y_min - 10.5f) * (48.0f / 47.0f)));
    int i_hi = min(47, (int)ceilf ((y_max + 11.5f) * (48.0f / 47.0f)));
    int k_lo = (i_lo * 48) & ~31;
    int k_hi = min(KD, ((i_hi + 1) * 48 + 31) & ~31);
    int nt   = (k_hi - k_lo) >> 5;

    // staging: per instruction 16 rows x 4 chunks; lane -> row (lane>>2), chunk lane&3,
    // source k-chunk pre-swizzled by row-pair key (lane>>3)&3
    int srow = lane >> 2;
    int sk   = (((lane & 3) ^ ((lane >> 3) & 3)) << 3);
    const f16* Abase = A  + (size_t)(m0 + w * 32 + srow) * KD + sk + k_lo;
    const f16* Bbase = Bt + (size_t)(n0 + w * 32 + srow) * KD + sk + k_lo;

    // fragment reads: row = 16*q + lrow; swizzled chunk = (lane>>4) ^ ((lrow>>1)&3)
    int lrow = lane & 15;
    int koe  = (((lane >> 4) ^ ((lane >> 1) & 3)) << 3);

    f32x4 acc[4][4] = {};

    #define STAGE(buf, koff)                                                          \
        do {                                                                          \
            gload16(Abase + (koff),            &As[(buf) * 4096 + w * 1024]);         \
            gload16(Abase + 16 * KD + (koff),  &As[(buf) * 4096 + w * 1024 + 512]);   \
            gload16(Bbase + (koff),            &Bs[(buf) * 4096 + w * 1024]);         \
            gload16(Bbase + 16 * KD + (koff),  &Bs[(buf) * 4096 + w * 1024 + 512]);   \
        } while (0)

    STAGE(0, 0);
    __syncthreads();

    for (int t = 0; t < nt; ++t) {
        int cur = t & 1;
        if (t + 1 < nt) STAGE(cur ^ 1, (t + 1) << 5);

        f16x8 af[4], bf[4];
        #pragma unroll
        for (int mi = 0; mi < 4; ++mi)
            af[mi] = *(const f16x8*)&As[cur * 4096 + (wr * 64 + mi * 16 + lrow) * 32 + koe];
        #pragma unroll
        for (int ni = 0; ni < 4; ++ni)
            bf[ni] = *(const f16x8*)&Bs[cur * 4096 + (wc * 64 + ni * 16 + lrow) * 32 + koe];

        #pragma unroll
        for (int mi = 0; mi < 4; ++mi)
            #pragma unroll
            for (int ni = 0; ni < 4; ++ni)
                acc[mi][ni] = __builtin_amdgcn_mfma_f32_16x16x32_f16(af[mi], bf[ni], acc[mi][ni], 0, 0, 0);

        __syncthreads();
    }
    #undef STAGE

    // epilogue: D row = (lane>>4)*4 + r, col = lane&15 (m89-verified C/D layout); clip + fold
    #pragma unroll
    for (int mi = 0; mi < 4; ++mi) {
        #pragma unroll
        for (int r = 0; r < 4; ++r) {
            int m  = m0 + wr * 64 + mi * 16 + (lane >> 4) * 4 + r;
            int bl = m >> 6, c = m & 63;
            int b  = bl >> 4, pr = (bl >> 2) & 3, pc = bl & 3;
            float* orow = out + ((size_t)(b * 64 + c) * HH + pr * 48) * HH + pc * 48;
            #pragma unroll
            for (int ni = 0; ni < 4; ++ni) {
                int n = n0 + wc * 64 + ni * 16 + (lane & 15);
                int y = n / 48, x = n - y * 48;
                float v = acc[mi][ni][r];
                v = fminf(fmaxf(v, 0.0f), 1.0f);
                orow[y * HH + x] = v;
            }
        }
    }
}

extern "C" void kernel_launch(void* const* d_in, const int* in_sizes, int n_in,
                              void* d_out, int out_size, void* d_ws, size_t ws_size,
                              hipStream_t stream) {
    const float* inp = (const float*)d_in[0];
    const float* sx  = (const float*)d_in[1];
    const float* sy  = (const float*)d_in[2];
    const float* op  = (const float*)d_in[3];
    float* out = (float*)d_out;

    char* ws = (char*)d_ws;
    f16* Kt = (f16*)ws;                      // 10616832 B  [2304][2304]
    f16* Ap = (f16*)(ws + 10616832);         // 18874368 B  [4096][2304]

    build_kt  <<<dim3(2592), dim3(256), 0, stream>>>(sx, sy, op, Kt);
    pack_A    <<<dim3(4608), dim3(256), 0, stream>>>(inp, Ap);
    gemm_splat<<<dim3(576),  dim3(256), 0, stream>>>(Ap, Kt, out);
}

// Round 5
// 137.647 us; speedup vs baseline: 1.1282x; 1.0054x over previous
//
#include <hip/hip_runtime.h>

// GaussianSplatter: out[(bl,c),(y,x)] = clip( sum_p A[(bl,c),p] * KY[p,y]*KX[p,x] )
// M=4096 (=64 patches * 64 ch), N=2304 (=48*48 pixels), K=2304 (=48*48 points)
// K-band: KY[p,y]!=0  <=>  y-10.5 < (47/48)*i < y+11.5  (i = p/48)
// GEMM: 128x128 tiles + XCD-chunked swizzle (R4) + XOR-swizzled LDS (0 conflicts)
//       + depth-3 pipeline: 3 LDS buffers, stage t+2, counted vmcnt(4) + raw s_barrier (T4).

#define NPTS 2304
#define KD   2304
#define HH   192

typedef _Float16 f16;
typedef _Float16 f16x8 __attribute__((ext_vector_type(8)));
typedef float f32x4 __attribute__((ext_vector_type(4)));

__device__ __forceinline__ void gload16(const f16* g, f16* l) {
    __builtin_amdgcn_global_load_lds((const __attribute__((address_space(1))) void*)g,
                                     (__attribute__((address_space(3))) void*)l,
                                     16, 0, 0);
}

// one bilinear tap of the padded 1-D gaussian: taps t in [13,33] hold exp(-(0.5t-11.5)^2 * inv2s)
__device__ __forceinline__ float gtap(float t, float inv2s) {
    float ax = 0.5f * t - 11.5f;
    float g = expf(-ax * ax * inv2s);
    return (t >= 12.5f && t <= 33.5f) ? g : 0.0f;
}

// Fused prep: blocks [0,2592) build Kt (VALU-bound), [2592,7200) pack A (BW-bound).
// Complementary pipes co-schedule on the same CUs (m114: overlap is free).
__global__ void prep(const float* __restrict__ inp,
                     const float* __restrict__ sx, const float* __restrict__ sy,
                     const float* __restrict__ op,
                     f16* __restrict__ Kt, f16* __restrict__ Ap) {
    int bid = blockIdx.x;
    if (bid < 2592) {
        // ---- build_kt: Kt[hw][p] = opacity[p]*KY(i,y)*KX(j,x), gaussians inline ----
        int idx = bid * 256 + threadIdx.x;          // 2304*288 = 663552 chunks
        int hw = idx / 288;
        int p0 = (idx - hw * 288) * 8;
        int y = hw / 48, x = hw - y * 48;
        int i = p0 / 48, j0 = p0 - i * 48;
        float py = (float)y + 23.5f - (47.0f / 48.0f) * (float)i;
        float y0 = floorf(py), fy = py - y0;
        f16x8 r;
        #pragma unroll
        for (int u = 0; u < 8; ++u) {
            int p = p0 + u;
            float sxv = sx[p], syv = sy[p], opv = op[p];
            float invx = 0.5f / (sxv * sxv);  // h-axis uses sigma_x (ref: xx2/sx2 on axis 1)
            float invy = 0.5f / (syv * syv);
            float ky = opv * (gtap(y0, invx) * (1.0f - fy) + gtap(y0 + 1.0f, invx) * fy);
            float px = (float)x + 23.5f - (47.0f / 48.0f) * (float)(j0 + u);
            float x0 = floorf(px), fx = px - x0;
            float kx = gtap(x0, invy) * (1.0f - fx) + gtap(x0 + 1.0f, invy) * fx;
            r[u] = (f16)(ky * kx);
        }
        *(f16x8*)(Kt + (size_t)hw * NPTS + p0) = r;
    } else {
        // ---- pack_A: A[m][p] fp16, m = bl*64+c, p = i*48+j ----
        int idx = (bid - 2592) * 256 + threadIdx.x; // 4096*288 chunks
        int m = idx / 288;
        int p0 = (idx - m * 288) * 8;
        int i = p0 / 48, j = p0 - i * 48;           // 8-chunk never crosses a patch row
        int bl = m >> 6, c = m & 63;
        int b = bl >> 4, pr = (bl >> 2) & 3, pc = bl & 3;
        const float* src = inp + ((size_t)(b * 64 + c) * HH + pr * 48 + i) * HH + pc * 48 + j;
        float4 a0 = *(const float4*)src;
        float4 a1 = *(const float4*)(src + 4);
        f16x8 r;
        r[0] = (f16)a0.x; r[1] = (f16)a0.y; r[2] = (f16)a0.z; r[3] = (f16)a0.w;
        r[4] = (f16)a1.x; r[5] = (f16)a1.y; r[6] = (f16)a1.z; r[7] = (f16)a1.w;
        *(f16x8*)(Ap + (size_t)m * KD + p0) = r;
    }
}

// C[m][n] = sum_k A[m][k] * Bt[n][k], k restricted to the i-band of this n-tile.
// LDS swizzle: slot (row, chunk cs) holds global k-chunk cs ^ ((row>>1)&3); inverse baked
// into gload_lds source offsets (rule 21 / m173). Depth-3 pipeline, counted vmcnt (T4).
__global__ __launch_bounds__(256) void gemm_splat(const f16* __restrict__ A,
                                                  const f16* __restrict__ Bt,
                                                  float* __restrict__ out) {
    __shared__ __attribute__((aligned(16))) f16 As[3 * 4096];   // [3][128][32]
    __shared__ __attribute__((aligned(16))) f16 Bs[3 * 4096];   // [3][128][32]

    int tid  = threadIdx.x;
    int lane = tid & 63;
    int w    = tid >> 6;
    int wr   = w >> 1, wc = w & 1;       // wave -> (64,64) output quadrant
    // XCD-chunked bijective swizzle: 576 blocks = 8 XCDs x 72 (= 4 m-panels x 18 n-tiles)
    int bx   = blockIdx.x;
    int wg   = (bx & 7) * 72 + (bx >> 3);
    int m0   = (wg / 18) * 128;
    int n0   = (wg % 18) * 128;

    // i-band for this n-tile (margin +-1 i; extra i's are exact zeros in Kt)
    int y_min = n0 / 48;
    int y_max = (n0 + 127) / 48;
    int i_lo = max(0,  (int)floorf((y_min - 10.5f) * (48.0f / 47.0f)));
    int i_hi = min(47, (int)ceilf ((y_max + 11.5f) * (48.0f / 47.0f)));
    int k_lo = (i_lo * 48) & ~31;
    int k_hi = min(KD, ((i_hi + 1) * 48 + 31) & ~31);
    int nt   = (k_hi - k_lo) >> 5;      // always >= 22 for this geometry

    // staging: per inst 16 rows x 4 chunks; lane -> row lane>>2, chunk lane&3,
    // source k-chunk pre-swizzled by row-pair key (lane>>3)&3
    int srow = lane >> 2;
    int sk   = (((lane & 3) ^ ((lane >> 3) & 3)) << 3);
    const f16* Abase = A  + (size_t)(m0 + w * 32 + srow) * KD + sk + k_lo;
    const f16* Bbase = Bt + (size_t)(n0 + w * 32 + srow) * KD + sk + k_lo;

    // fragment reads: row = 16*q + lrow; swizzled chunk = (lane>>4) ^ ((lrow>>1)&3)
    int lrow = lane & 15;
    int koe  = (((lane >> 4) ^ ((lane >> 1) & 3)) << 3);

    f32x4 acc[4][4] = {};

    // 4 gload16 per wave per stage -> counted wait vmcnt(4) keeps newest stage in flight
    #define STAGE(slot, koff)                                                   \
        do {                                                                    \
            f16* as_ = &As[(slot) * 4096 + w * 1024];                           \
            f16* bs_ = &Bs[(slot) * 4096 + w * 1024];                           \
            gload16(Abase + (koff),           as_);                             \
            gload16(Abase + 16 * KD + (koff), as_ + 512);                       \
            gload16(Bbase + (koff),           bs_);                             \
            gload16(Bbase + 16 * KD + (koff), bs_ + 512);                       \
        } while (0)

    // prologue: stage tiles 0,1; retire tile 0 (8 outstanding -> wait 4)
    STAGE(0, 0);
    STAGE(1, 32);
    asm volatile("s_waitcnt vmcnt(4)" ::: "memory");
    __builtin_amdgcn_s_barrier();
    __builtin_amdgcn_sched_barrier(0);

    int rs = 0, ps = 2;   // read slot t%3; stage slot (t+2)%3 == previous read slot
    for (int t = 0; t < nt; ++t) {
        if (t + 2 < nt) STAGE(ps, (t + 2) << 5);

        const f16* as_ = &As[rs * 4096];
        const f16* bs_ = &Bs[rs * 4096];
        f16x8 af[4], bf[4];
        #pragma unroll
        for (int mi = 0; mi < 4; ++mi)
            af[mi] = *(const f16x8*)&as_[(wr * 64 + mi * 16 + lrow) * 32 + koe];
        #pragma unroll
        for (int ni = 0; ni < 4; ++ni)
            bf[ni] = *(const f16x8*)&bs_[(wc * 64 + ni * 16 + lrow) * 32 + koe];

        __builtin_amdgcn_s_setprio(1);
        #pragma unroll
        for (int mi = 0; mi < 4; ++mi)
            #pragma unroll
            for (int ni = 0; ni < 4; ++ni)
                acc[mi][ni] = __builtin_amdgcn_mfma_f32_16x16x32_f16(af[mi], bf[ni], acc[mi][ni], 0, 0, 0);
        __builtin_amdgcn_s_setprio(0);

        // retire tile t+1 before the barrier; keep tile t+2's loads in flight
        if (t + 2 < nt) {
            asm volatile("s_waitcnt vmcnt(4)" ::: "memory");
        } else if (t + 1 < nt) {
            asm volatile("s_waitcnt vmcnt(0)" ::: "memory");
        }
        if (t + 1 < nt) {
            __builtin_amdgcn_s_barrier();
            __builtin_amdgcn_sched_barrier(0);
        }
        ps = rs;
        rs = (rs == 2) ? 0 : rs + 1;
    }
    #undef STAGE

    // epilogue: D row = (lane>>4)*4 + r, col = lane&15 (m89-verified C/D layout); clip + fold
    #pragma unroll
    for (int mi = 0; mi < 4; ++mi) {
        #pragma unroll
        for (int r = 0; r < 4; ++r) {
            int m  = m0 + wr * 64 + mi * 16 + (lane >> 4) * 4 + r;
            int bl = m >> 6, c = m & 63;
            int b  = bl >> 4, pr = (bl >> 2) & 3, pc = bl & 3;
            float* orow = out + ((size_t)(b * 64 + c) * HH + pr * 48) * HH + pc * 48;
            #pragma unroll
            for (int ni = 0; ni < 4; ++ni) {
                int n = n0 + wc * 64 + ni * 16 + (lane & 15);
                int y = n / 48, x = n - y * 48;
                float v = acc[mi][ni][r];
                v = fminf(fmaxf(v, 0.0f), 1.0f);
                orow[y * HH + x] = v;
            }
        }
    }
}

extern "C" void kernel_launch(void* const* d_in, const int* in_sizes, int n_in,
                              void* d_out, int out_size, void* d_ws, size_t ws_size,
                              hipStream_t stream) {
    const float* inp = (const float*)d_in[0];
    const float* sx  = (const float*)d_in[1];
    const float* sy  = (const float*)d_in[2];
    const float* op  = (const float*)d_in[3];
    float* out = (float*)d_out;

    char* ws = (char*)d_ws;
    f16* Kt = (f16*)ws;                      // 10616832 B  [2304][2304]
    f16* Ap = (f16*)(ws + 10616832);         // 18874368 B  [4096][2304]

    prep      <<<dim3(7200), dim3(256), 0, stream>>>(inp, sx, sy, op, Kt, Ap);
    gemm_splat<<<dim3(576),  dim3(256), 0, stream>>>(Ap, Kt, out);
}

// Round 8
// 128.528 us; speedup vs baseline: 1.2082x; 1.0710x over previous
//
#include <hip/hip_runtime.h>

// GaussianSplatter: out[(bl,c),(y,x)] = clip( sum_p A[(bl,c),p] * KY[p,y]*KX[p,x] )
// M=4096 (=64 patches * 64 ch), N=2304 (=48*48 pixels), K=2304 (=48*48 points)
// R8: all proven-passing parts. GEMM = R5 verbatim (depth-3 pipeline, counted vmcnt,
// XOR-swizzled LDS w/ 0 conflicts, XCD-chunked swizzle, FULL Kt). Prep = R1/R2-proven
// table route: build_tabs (small) then fused {Kt = KY*KX product, pack_A}.

#define NPTS 2304
#define KD   2304
#define HH   192

typedef _Float16 f16;
typedef _Float16 f16x8 __attribute__((ext_vector_type(8)));
typedef float f32x4 __attribute__((ext_vector_type(4)));

__device__ __forceinline__ void gload16(const f16* g, f16* l) {
    __builtin_amdgcn_global_load_lds((const __attribute__((address_space(1))) void*)g,
                                     (__attribute__((address_space(3))) void*)l,
                                     16, 0, 0);
}

// one bilinear tap of the padded 1-D gaussian: taps t in [13,33] hold exp(-(0.5t-11.5)^2 * inv2s)
__device__ __forceinline__ float gtap(float t, float inv2s) {
    float ax = 0.5f * t - 11.5f;
    float g = expf(-ax * ax * inv2s);
    return (t >= 12.5f && t <= 33.5f) ? g : 0.0f;
}

// KY_T[y][p] (opacity folded), KX_T[x][p]  -- R1-verbatim (passed)
__global__ void build_tabs(const float* __restrict__ sx, const float* __restrict__ sy,
                           const float* __restrict__ op,
                           float* __restrict__ KY_T, float* __restrict__ KX_T) {
    int flat = blockIdx.x * 256 + threadIdx.x;      // 48*2304 = 110592
    if (flat >= 48 * NPTS) return;
    int pos = flat / NPTS;
    int p   = flat - pos * NPTS;
    int i = p / 48;
    int j = p - i * 48;
    float sxv = sx[p], syv = sy[p], opv = op[p];
    float invx = 0.5f / (sxv * sxv);  // h-axis uses sigma_x (reference: xx2/sx2 on axis 1)
    float invy = 0.5f / (syv * syv);

    float py = (float)pos + 23.5f - (47.0f / 48.0f) * (float)i;
    float y0 = floorf(py), fy = py - y0;
    KY_T[flat] = opv * (gtap(y0, invx) * (1.0f - fy) + gtap(y0 + 1.0f, invx) * fy);

    float px = (float)pos + 23.5f - (47.0f / 48.0f) * (float)j;
    float x0 = floorf(px), fx = px - x0;
    KX_T[flat] = gtap(x0, invy) * (1.0f - fx) + gtap(x0 + 1.0f, invy) * fx;
}

// Fused: blocks [0,2592) Kt[hw][p] = KY_T[y][p]*KX_T[x][p] (R2-verbatim, passed);
//        blocks [2592,7200) pack_A (R5-verbatim, passed).
__global__ void prep2(const float* __restrict__ inp,
                      const float* __restrict__ KY_T, const float* __restrict__ KX_T,
                      f16* __restrict__ Kt, f16* __restrict__ Ap) {
    int bid = blockIdx.x;
    if (bid < 2592) {
        int idx = bid * 256 + threadIdx.x;          // 2304*288 = 663552 chunks
        int hw = idx / 288;
        int p0 = (idx - hw * 288) * 8;
        int y = hw / 48, x = hw - y * 48;
        const float4* ky = (const float4*)(KY_T + (size_t)y * NPTS + p0);
        const float4* kx = (const float4*)(KX_T + (size_t)x * NPTS + p0);
        float4 a0 = ky[0], a1 = ky[1];
        float4 b0 = kx[0], b1 = kx[1];
        f16x8 r;
        r[0] = (f16)(a0.x * b0.x); r[1] = (f16)(a0.y * b0.y);
        r[2] = (f16)(a0.z * b0.z); r[3] = (f16)(a0.w * b0.w);
        r[4] = (f16)(a1.x * b1.x); r[5] = (f16)(a1.y * b1.y);
        r[6] = (f16)(a1.z * b1.z); r[7] = (f16)(a1.w * b1.w);
        *(f16x8*)(Kt + (size_t)hw * NPTS + p0) = r;
    } else {
        int idx = (bid - 2592) * 256 + threadIdx.x; // 4096*288 chunks
        int m = idx / 288;
        int p0 = (idx - m * 288) * 8;
        int i = p0 / 48, j = p0 - i * 48;           // 8-chunk never crosses a patch row
        int bl = m >> 6, c = m & 63;
        int b = bl >> 4, pr = (bl >> 2) & 3, pc = bl & 3;
        const float* src = inp + ((size_t)(b * 64 + c) * HH + pr * 48 + i) * HH + pc * 48 + j;
        float4 a0 = *(const float4*)src;
        float4 a1 = *(const float4*)(src + 4);
        f16x8 r;
        r[0] = (f16)a0.x; r[1] = (f16)a0.y; r[2] = (f16)a0.z; r[3] = (f16)a0.w;
        r[4] = (f16)a1.x; r[5] = (f16)a1.y; r[6] = (f16)a1.z; r[7] = (f16)a1.w;
        *(f16x8*)(Ap + (size_t)m * KD + p0) = r;
    }
}

// C[m][n] = sum_k A[m][k] * Bt[n][k], k restricted to the i-band of this n-tile.
// R5-verbatim (passed): XOR-swizzled LDS (0 conflicts), depth-3 pipeline, counted vmcnt.
__global__ __launch_bounds__(256) void gemm_splat(const f16* __restrict__ A,
                                                  const f16* __restrict__ Bt,
                                                  float* __restrict__ out) {
    __shared__ __attribute__((aligned(16))) f16 As[3 * 4096];   // [3][128][32]
    __shared__ __attribute__((aligned(16))) f16 Bs[3 * 4096];   // [3][128][32]

    int tid  = threadIdx.x;
    int lane = tid & 63;
    int w    = tid >> 6;
    int wr   = w >> 1, wc = w & 1;       // wave -> (64,64) output quadrant
    // XCD-chunked bijective swizzle: 576 blocks = 8 XCDs x 72 (= 4 m-panels x 18 n-tiles)
    int bx   = blockIdx.x;
    int wg   = (bx & 7) * 72 + (bx >> 3);
    int m0   = (wg / 18) * 128;
    int n0   = (wg % 18) * 128;

    // i-band for this n-tile (margin +-1 i; extra i's are exact zeros in Kt)
    int y_min = n0 / 48;
    int y_max = (n0 + 127) / 48;
    int i_lo = max(0,  (int)floorf((y_min - 10.5f) * (48.0f / 47.0f)));
    int i_hi = min(47, (int)ceilf ((y_max + 11.5f) * (48.0f / 47.0f)));
    int k_lo = (i_lo * 48) & ~31;
    int k_hi = min(KD, ((i_hi + 1) * 48 + 31) & ~31);
    int nt   = (k_hi - k_lo) >> 5;      // always >= 22 for this geometry

    // staging: per inst 16 rows x 4 chunks; lane -> row lane>>2, chunk lane&3,
    // source k-chunk pre-swizzled by row-pair key (lane>>3)&3
    int srow = lane >> 2;
    int sk   = (((lane & 3) ^ ((lane >> 3) & 3)) << 3);
    const f16* Abase = A  + (size_t)(m0 + w * 32 + srow) * KD + sk + k_lo;
    const f16* Bbase = Bt + (size_t)(n0 + w * 32 + srow) * KD + sk + k_lo;

    // fragment reads: row = 16*q + lrow; swizzled chunk = (lane>>4) ^ ((lrow>>1)&3)
    int lrow = lane & 15;
    int koe  = (((lane >> 4) ^ ((lane >> 1) & 3)) << 3);

    f32x4 acc[4][4] = {};

    // 4 gload16 per wave per stage -> counted wait vmcnt(4) keeps newest stage in flight
    #define STAGE(slot, koff)                                                   \
        do {                                                                    \
            f16* as_ = &As[(slot) * 4096 + w * 1024];                           \
            f16* bs_ = &Bs[(slot) * 4096 + w * 1024];                           \
            gload16(Abase + (koff),           as_);                             \
            gload16(Abase + 16 * KD + (koff), as_ + 512);                       \
            gload16(Bbase + (koff),           bs_);                             \
            gload16(Bbase + 16 * KD + (koff), bs_ + 512);                       \
        } while (0)

    // prologue: stage tiles 0,1; retire tile 0 (8 outstanding -> wait 4)
    STAGE(0, 0);
    STAGE(1, 32);
    asm volatile("s_waitcnt vmcnt(4)" ::: "memory");
    __builtin_amdgcn_s_barrier();
    __builtin_amdgcn_sched_barrier(0);

    int rs = 0, ps = 2;   // read slot t%3; stage slot (t+2)%3 == previous read slot
    for (int t = 0; t < nt; ++t) {
        if (t + 2 < nt) STAGE(ps, (t + 2) << 5);

        const f16* as_ = &As[rs * 4096];
        const f16* bs_ = &Bs[rs * 4096];
        f16x8 af[4], bf[4];
        #pragma unroll
        for (int mi = 0; mi < 4; ++mi)
            af[mi] = *(const f16x8*)&as_[(wr * 64 + mi * 16 + lrow) * 32 + koe];
        #pragma unroll
        for (int ni = 0; ni < 4; ++ni)
            bf[ni] = *(const f16x8*)&bs_[(wc * 64 + ni * 16 + lrow) * 32 + koe];

        __builtin_amdgcn_s_setprio(1);
        #pragma unroll
        for (int mi = 0; mi < 4; ++mi)
            #pragma unroll
            for (int ni = 0; ni < 4; ++ni)
                acc[mi][ni] = __builtin_amdgcn_mfma_f32_16x16x32_f16(af[mi], bf[ni], acc[mi][ni], 0, 0, 0);
        __builtin_amdgcn_s_setprio(0);

        // retire tile t+1 before the barrier; keep tile t+2's loads in flight
        if (t + 2 < nt) {
            asm volatile("s_waitcnt vmcnt(4)" ::: "memory");
        } else if (t + 1 < nt) {
            asm volatile("s_waitcnt vmcnt(0)" ::: "memory");
        }
        if (t + 1 < nt) {
            __builtin_amdgcn_s_barrier();
            __builtin_amdgcn_sched_barrier(0);
        }
        ps = rs;
        rs = (rs == 2) ? 0 : rs + 1;
    }
    #undef STAGE

    // epilogue: D row = (lane>>4)*4 + r, col = lane&15 (m89-verified C/D layout); clip + fold
    #pragma unroll
    for (int mi = 0; mi < 4; ++mi) {
        #pragma unroll
        for (int r = 0; r < 4; ++r) {
            int m  = m0 + wr * 64 + mi * 16 + (lane >> 4) * 4 + r;
            int bl = m >> 6, c = m & 63;
            int b  = bl >> 4, pr = (bl >> 2) & 3, pc = bl & 3;
            float* orow = out + ((size_t)(b * 64 + c) * HH + pr * 48) * HH + pc * 48;
            #pragma unroll
            for (int ni = 0; ni < 4; ++ni) {
                int n = n0 + wc * 64 + ni * 16 + (lane & 15);
                int y = n / 48, x = n - y * 48;
                float v = acc[mi][ni][r];
                v = fminf(fmaxf(v, 0.0f), 1.0f);
                orow[y * HH + x] = v;
            }
        }
    }
}

extern "C" void kernel_launch(void* const* d_in, const int* in_sizes, int n_in,
                              void* d_out, int out_size, void* d_ws, size_t ws_size,
                              hipStream_t stream) {
    const float* inp = (const float*)d_in[0];
    const float* sx  = (const float*)d_in[1];
    const float* sy  = (const float*)d_in[2];
    const float* op  = (const float*)d_in[3];
    float* out = (float*)d_out;

    char* ws = (char*)d_ws;
    float* KY_T = (float*)ws;                         //   442368 B
    float* KX_T = (float*)(ws + 442368);              //   442368 B
    f16*   Kt   = (f16*)(ws + 884736);                // 10616832 B  [2304][2304]
    f16*   Ap   = (f16*)(ws + 884736 + 10616832);     // 18874368 B  [4096][2304]

    build_tabs<<<dim3(432),  dim3(256), 0, stream>>>(sx, sy, op, KY_T, KX_T);
    prep2     <<<dim3(7200), dim3(256), 0, stream>>>(inp, KY_T, KX_T, Kt, Ap);
    gemm_splat<<<dim3(576),  dim3(256), 0, stream>>>(Ap, Kt, out);
}